// Round 20
// baseline (124.441 us; speedup 1.0000x reference)
//
#include <hip/hip_runtime.h>
#include <hip/hip_fp16.h>

#define N_NODES 50000
#define N_EDGES 600000
#define CAP 64   // bucket capacity per node (max degree ~40 for Poisson(12))
#define GEMM1_BLOCKS ((N_NODES + 63) / 64)        // 782 (first in fused grid)
#define HIST_BLOCKS ((N_EDGES / 4 + 255) / 256)   // 586
// pipeline split: h rows [0,N1) ready after K1 -> gemm_l2 tiles [0,T1) in K2
#define N1 33280                                   // = 520*64, divisible by 4
#define K1_BLOCKS (N1 / 4)                         // 8320
#define GRB2 ((N_NODES - N1 + 3) / 4)              // 4180 (g_relu part of K2)
#define T1 (N1 / 64)                               // 520 gemm tiles in K2
#define T_TAIL (GEMM1_BLOCKS - T1)                 // 262 tiles in K3

typedef _Float16 f16;
typedef f16 f16x8 __attribute__((ext_vector_type(8)));
typedef float f32x4 __attribute__((ext_vector_type(4)));
typedef unsigned int u32;
typedef unsigned long long u64;
typedef u32 u32x2 __attribute__((ext_vector_type(2)));
typedef u32 u32x4 __attribute__((ext_vector_type(4)));

#define WSCALE 33554432.0f   // 2^25

__device__ __forceinline__ float wsum_of(u64 dcv) {
    return (float)(u32)(dcv & 0xFFFFFFFFu) * (1.0f / WSCALE);
}

// ---------------- prep: dc init + f16 weights (one launch) ----------------

__global__ __launch_bounds__(256) void prep(const float* __restrict__ W1,
                                            const float* __restrict__ Wmu,
                                            const float* __restrict__ Wls,
                                            f16* __restrict__ Wc1,
                                            f16* __restrict__ Wc2,
                                            u64* __restrict__ dc, int n) {
    int i = blockIdx.x * 256 + threadIdx.x;
    if (i < 16384) {
        Wc1[i] = (f16)W1[i];
        Wc2[i] = (f16)((i < 8192) ? Wmu[i] : Wls[i - 8192]);
    }
    if (i < n) dc[i] = 0ULL;
}

// ---------------- GEMM device body: sA-only LDS (16KB), W direct from L2 ------

template<bool A_F16>
__device__ __forceinline__ void gemm_body(const void* __restrict__ Aptr,
                                          const f16* __restrict__ Wc,
                                          f16* __restrict__ Cout, int M, int bid,
                                          f16* sA) {
    const int tid = threadIdx.x;
    const int row0 = bid * 64;

    if (A_F16) {
        const u32x4* src = (const u32x4*)Aptr;   // row-major [M][128] f16
        u32x4* dst = (u32x4*)sA;
        #pragma unroll
        for (int i = 0; i < 4; ++i) {
            int c = tid + i * 256;
            int r = c >> 4, ch = c & 15;
            int gr = row0 + r;
            u32x4 v = {};
            if (gr < M) v = src[gr * 16 + ch];
            dst[r * 16 + (ch ^ (r & 15))] = v;
        }
    } else {
        const float4* src = (const float4*)Aptr;   // fp32 x, row-major [M][128]
        u32x4* dst = (u32x4*)sA;
        #pragma unroll
        for (int i = 0; i < 4; ++i) {
            int c = tid + i * 256;
            int r = c >> 4, ch = c & 15;
            int gr = row0 + r;
            f16x8 h = {};
            if (gr < M) {
                float4 a = src[gr * 32 + ch * 2];
                float4 b = src[gr * 32 + ch * 2 + 1];
                h[0] = (f16)a.x; h[1] = (f16)a.y; h[2] = (f16)a.z; h[3] = (f16)a.w;
                h[4] = (f16)b.x; h[5] = (f16)b.y; h[6] = (f16)b.z; h[7] = (f16)b.w;
            }
            dst[r * 16 + (ch ^ (r & 15))] = *(const u32x4*)&h;
        }
    }
    __syncthreads();

    const int wave = tid >> 6, lane = tid & 63;
    const int m = lane & 15, kq = lane >> 4;
    const int wcol0 = wave * 32;

    f32x4 acc[4][2] = {};
    const f16x8* sa = (const f16x8*)sA;
    const f16x8* W8 = (const f16x8*)Wc;    // [128 rows][16 chunks]

    #pragma unroll
    for (int ks = 0; ks < 4; ++ks) {
        int cidx = ks * 4 + kq;
        f16x8 bfrag[2];
        #pragma unroll
        for (int cf = 0; cf < 2; ++cf)
            bfrag[cf] = W8[(wcol0 + cf * 16 + m) * 16 + cidx];   // direct from L2
        #pragma unroll
        for (int rf = 0; rf < 4; ++rf) {
            int ar = rf * 16 + m;
            f16x8 afrag = sa[ar * 16 + (cidx ^ m)];
            #pragma unroll
            for (int cf = 0; cf < 2; ++cf)
                acc[rf][cf] = __builtin_amdgcn_mfma_f32_16x16x32_f16(
                    afrag, bfrag[cf], acc[rf][cf], 0, 0, 0);
        }
    }

    __syncthreads();                 // done reading sA; reuse as output tile
    #pragma unroll
    for (int rf = 0; rf < 4; ++rf)
        #pragma unroll
        for (int cf = 0; cf < 2; ++cf)
            #pragma unroll
            for (int r = 0; r < 4; ++r)
                sA[(rf * 16 + kq * 4 + r) * 128 + wcol0 + cf * 16 + m] =
                    (f16)acc[rf][cf][r];
    __syncthreads();
    {
        const u32x4* src = (const u32x4*)sA;
        u32x4* dst = (u32x4*)Cout;
        #pragma unroll
        for (int i = 0; i < 4; ++i) {
            int c = tid + i * 256;
            int r = c >> 4, ch = c & 15;
            int gr = row0 + r;
            if (gr < M) dst[gr * 16 + ch] = src[c];
        }
    }
}

// ---------------- FUSED: GEMM1 blocks first + hist_fill4 blocks ----------------

__global__ __launch_bounds__(256) void gemm1_hist(const float* __restrict__ x,
                                                  const f16* __restrict__ Wc1,
                                                  f16* __restrict__ Cout,
                                                  const int* __restrict__ ei,
                                                  const float* __restrict__ ew,
                                                  u64* __restrict__ dc,
                                                  u32x2* __restrict__ sed8,
                                                  int M, int E) {
    __shared__ f16 sA[64 * 128];
    if (blockIdx.x < GEMM1_BLOCKS) {
        gemm_body<false>(x, Wc1, Cout, M, blockIdx.x, sA);
        return;
    }
    // ---- hist_fill4 part: 4 consecutive edges per thread ----
    int t = (blockIdx.x - GEMM1_BLOCKS) * 256 + threadIdx.x;
    int e = 4 * t;
    if (e >= E) return;                       // E % 4 == 0 -> all 4 valid
    int4  r = *reinterpret_cast<const int4*>(ei + e);
    int4  c = *reinterpret_cast<const int4*>(ei + E + e);
    float4 w = *reinterpret_cast<const float4*>(ew + e);

    u64 old0 = 0, old1 = 0, old2 = 0, old3 = 0;
    bool k0 = r.x != c.x, k1 = r.y != c.y, k2 = r.z != c.z, k3 = r.w != c.w;
    if (k0) old0 = atomicAdd(&dc[c.x], (1ULL << 32) | (u64)(u32)__float2uint_rn(w.x * WSCALE));
    if (k1) old1 = atomicAdd(&dc[c.y], (1ULL << 32) | (u64)(u32)__float2uint_rn(w.y * WSCALE));
    if (k2) old2 = atomicAdd(&dc[c.z], (1ULL << 32) | (u64)(u32)__float2uint_rn(w.z * WSCALE));
    if (k3) old3 = atomicAdd(&dc[c.w], (1ULL << 32) | (u64)(u32)__float2uint_rn(w.w * WSCALE));

    u32x2 rec;
    if (k0) { rec.x = __float_as_uint(w.x); rec.y = (u32)r.x; sed8[(size_t)c.x * CAP + (u32)(old0 >> 32)] = rec; }
    if (k1) { rec.x = __float_as_uint(w.y); rec.y = (u32)r.y; sed8[(size_t)c.y * CAP + (u32)(old1 >> 32)] = rec; }
    if (k2) { rec.x = __float_as_uint(w.z); rec.y = (u32)r.z; sed8[(size_t)c.z * CAP + (u32)(old2 >> 32)] = rec; }
    if (k3) { rec.x = __float_as_uint(w.w); rec.y = (u32)r.w; sed8[(size_t)c.w * CAP + (u32)(old3 >> 32)] = rec; }
}

// ---------------- bucket gather + fused epilogues (row-major [N][128] f16 src) ----

__device__ __forceinline__ void bucket_gather(const u32x2* __restrict__ eb,
                                              const u32* __restrict__ srcu,
                                              int pad, int lane,
                                              float& a0, float& a1) {
    for (int p = 0; p < pad; p += 16) {
        #pragma unroll
        for (int j = 0; j < 16; ++j) {
            u32x2 d = eb[p + j];
            float nm = __uint_as_float(d.x);
            __half2 hv = *reinterpret_cast<const __half2*>(&srcu[d.y + lane]);
            float2 v = __half22float2(hv);
            a0 += nm * v.x;
            a1 += nm * v.y;
        }
    }
}

// gather_relu body WITH fused rewrite prologue (R18-proven), callable per wid.
__device__ __forceinline__ void grelu_body(u32x2* __restrict__ sed8,
                                           const u64* __restrict__ dc,
                                           const f16* __restrict__ xw,
                                           const float* __restrict__ b,
                                           f16* __restrict__ h, int n,
                                           int wid, int lane) {
    u32x2* eb = sed8 + (size_t)wid * CAP;
    u64 dcw = dc[wid];
    int cnt = (int)(dcw >> 32);
    int pad = (cnt + 15) & ~15;

    // ---- rewrite prologue (lane-parallel, wave-local) ----
    if (lane < pad) {
        u32x2 rec;
        if (lane < cnt) {
            u32x2 d = eb[lane];
            int r = (int)d.y;
            float w = __uint_as_float(d.x);
            float dis_own = rsqrtf(1.0f + wsum_of(dcw));
            float dis_r   = rsqrtf(1.0f + wsum_of(dc[r]));
            rec.x = __float_as_uint(dis_own * w * dis_r);
            rec.y = (u32)r * 64u;
        } else {
            rec.x = 0u; rec.y = (u32)(wid * 64);   // zero-weight pad
        }
        eb[lane] = rec;
    }

    const u32* srcu = (const u32*)xw;
    float a0 = 0.f, a1 = 0.f;
    bucket_gather(eb, srcu, pad, lane, a0, a1);
    float inv = 1.0f / (1.0f + wsum_of(dcw));   // 1/deg
    float2 xv = __half22float2(*reinterpret_cast<const __half2*>(&srcu[wid * 64 + lane]));
    float2 bb = reinterpret_cast<const float2*>(b)[lane];
    float o0 = fmaxf(a0 + xv.x * inv + bb.x, 0.f);
    float o1 = fmaxf(a1 + xv.y * inv + bb.y, 0.f);
    reinterpret_cast<__half2*>(h)[wid * 64 + lane] = __floats2half2_rn(o0, o1);
}

// K1: gather_relu for nodes [0, N1)
__global__ __launch_bounds__(256) void gather_relu_k1(u32x2* __restrict__ sed8,
                                                      const u64* __restrict__ dc,
                                                      const f16* __restrict__ xw,
                                                      const float* __restrict__ b,
                                                      f16* __restrict__ h, int n) {
    int wid = blockIdx.x * 4 + (threadIdx.x >> 6);
    int lane = threadIdx.x & 63;
    if (wid >= N1) return;
    grelu_body(sed8, dc, xw, b, h, n, wid, lane);
}

// K2: FUSED gather_relu [N1,N) (first: longer pole, K3 depends on it)
//     + gemm_l2 tiles [0, T1) (h rows [0,N1) ready after K1)
__global__ __launch_bounds__(256) void grelu_gemm2(u32x2* __restrict__ sed8,
                                                   const u64* __restrict__ dc,
                                                   const f16* __restrict__ xw,
                                                   const float* __restrict__ b,
                                                   f16* __restrict__ h,
                                                   const f16* __restrict__ Wc2,
                                                   f16* __restrict__ hw, int n) {
    __shared__ f16 sA[64 * 128];
    if (blockIdx.x < GRB2) {
        int wid = N1 + blockIdx.x * 4 + (threadIdx.x >> 6);
        int lane = threadIdx.x & 63;
        if (wid >= n) return;
        grelu_body(sed8, dc, xw, b, h, n, wid, lane);
        return;
    }
    gemm_body<true>(h, Wc2, hw, n, blockIdx.x - GRB2, sA);   // tiles 0..T1-1
}

// K3: gemm_l2 tail tiles [T1, 782)
__global__ __launch_bounds__(256) void gemm_l2_tail(const f16* __restrict__ Aptr,
                                                    const f16* __restrict__ Wc,
                                                    f16* __restrict__ Cout, int M) {
    __shared__ f16 sA[64 * 128];
    gemm_body<true>(Aptr, Wc, Cout, M, blockIdx.x + T1, sA);
}

__global__ __launch_bounds__(256) void gather_out(const u32x2* __restrict__ sed8,
                                                  const u64* __restrict__ dc,
                                                  const f16* __restrict__ hw,  // [n][128]
                                                  const float* __restrict__ bmu,
                                                  const float* __restrict__ bls,
                                                  float* __restrict__ out, int n) {
    int wid = blockIdx.x * 4 + (threadIdx.x >> 6);
    int lane = threadIdx.x & 63;
    if (wid >= n) return;
    const u32* srcu = (const u32*)hw;
    u64 dcw = dc[wid];
    int cnt = (int)(dcw >> 32);
    int pad = (cnt + 15) & ~15;
    float a0 = 0.f, a1 = 0.f;
    bucket_gather(sed8 + (size_t)wid * CAP, srcu, pad, lane, a0, a1);
    float inv = 1.0f / (1.0f + wsum_of(dcw));
    float2 xv = __half22float2(*reinterpret_cast<const __half2*>(&srcu[wid * 64 + lane]));
    float2 bb = (lane < 32) ? reinterpret_cast<const float2*>(bmu)[lane]
                            : reinterpret_cast<const float2*>(bls)[lane - 32];
    float2 o = make_float2(a0 + xv.x * inv + bb.x, a1 + xv.y * inv + bb.y);
    // cols 0..63 (lanes 0..31) -> mu ; cols 64..127 (lanes 32..63) -> logstd
    if (lane < 32)
        reinterpret_cast<float2*>(out)[wid * 32 + lane] = o;
    else
        reinterpret_cast<float2*>(out + (size_t)n * 64)[wid * 32 + (lane - 32)] = o;
}

extern "C" void kernel_launch(void* const* d_in, const int* in_sizes, int n_in,
                              void* d_out, int out_size, void* d_ws, size_t ws_size,
                              hipStream_t stream) {
    const float* x   = (const float*)d_in[0];
    const int*   ei  = (const int*)d_in[1];
    const float* ew  = (const float*)d_in[2];
    const float* W1  = (const float*)d_in[3];
    const float* b1  = (const float*)d_in[4];
    const float* Wmu = (const float*)d_in[5];
    const float* bmu = (const float*)d_in[6];
    const float* Wls = (const float*)d_in[7];
    const float* bls = (const float*)d_in[8];
    float* out = (float*)d_out;

    // workspace layout (u32 units; all bases 16B-aligned)
    u64*   dc    = (u64*)d_ws;                       // 50000 u64 (100000 u32)
    u32x2* sed8  = (u32x2*)((u32*)d_ws + 100000);    // N*CAP u32x2 (25.6 MB)
    f16*   Wc1   = (f16*)((u32*)d_ws + 6500000);     // 16384 f16
    f16*   Wc2   = (f16*)((u32*)d_ws + 6508192);     // 16384 f16
    f16*   Abuf  = (f16*)((u32*)d_ws + 6516384);     // [N][128] f16 (xw -> hw)
    f16*   Hbuf  = (f16*)((u32*)d_ws + 9716384);     // [N][128] f16 (h)

    const int N = N_NODES, E = N_EDGES;
    const int NB = (N + 255) / 256;   // 196
    const int WB = (N + 3) / 4;       // wave-per-node kernels: 4 waves/block

    prep<<<NB, 256, 0, stream>>>(W1, Wmu, Wls, Wc1, Wc2, dc, N);

    // FUSED: layer-1 GEMM (first) + bucket-CSR histogram/fill
    gemm1_hist<<<GEMM1_BLOCKS + HIST_BLOCKS, 256, 0, stream>>>(
        x, Wc1, Abuf, ei, ew, dc, sed8, N, E);

    // pipeline-split gather_relu / gemm_l2
    gather_relu_k1<<<K1_BLOCKS, 256, 0, stream>>>(sed8, dc, Abuf, b1, Hbuf, N);
    grelu_gemm2<<<GRB2 + T1, 256, 0, stream>>>(sed8, dc, Abuf, b1, Hbuf, Wc2, Abuf, N);
    gemm_l2_tail<<<T_TAIL, 256, 0, stream>>>(Hbuf, Wc2, Abuf, N);

    gather_out<<<WB, 256, 0, stream>>>(sed8, dc, Abuf, bmu, bls, out, N);
}

// Round 21
// 119.231 us; speedup vs baseline: 1.0437x; 1.0437x over previous
//
#include <hip/hip_runtime.h>
#include <hip/hip_fp16.h>

#define N_NODES 50000
#define N_EDGES 600000
#define CAP 64   // bucket capacity per node (max degree ~40 for Poisson(12))
#define GEMM1_BLOCKS ((N_NODES + 63) / 64)        // 782 (first in fused grid)
#define HIST_BLOCKS ((N_EDGES / 4 + 255) / 256)   // 586

typedef _Float16 f16;
typedef f16 f16x8 __attribute__((ext_vector_type(8)));
typedef float f32x4 __attribute__((ext_vector_type(4)));
typedef unsigned int u32;
typedef unsigned long long u64;
typedef u32 u32x2 __attribute__((ext_vector_type(2)));
typedef u32 u32x4 __attribute__((ext_vector_type(4)));

#define WSCALE 33554432.0f   // 2^25

__device__ __forceinline__ float wsum_of(u64 dcv) {
    return (float)(u32)(dcv & 0xFFFFFFFFu) * (1.0f / WSCALE);
}

// ---------------- prep: dc init + f16 weights (one launch) ----------------

__global__ __launch_bounds__(256) void prep(const float* __restrict__ W1,
                                            const float* __restrict__ Wmu,
                                            const float* __restrict__ Wls,
                                            f16* __restrict__ Wc1,
                                            f16* __restrict__ Wc2,
                                            u64* __restrict__ dc, int n) {
    int i = blockIdx.x * 256 + threadIdx.x;
    if (i < 16384) {
        Wc1[i] = (f16)W1[i];
        Wc2[i] = (f16)((i < 8192) ? Wmu[i] : Wls[i - 8192]);
    }
    if (i < n) dc[i] = 0ULL;
}

// ---------------- GEMM device body: sA-only LDS (16KB), W direct from L2 ------

template<bool A_F16>
__device__ __forceinline__ void gemm_body(const void* __restrict__ Aptr,
                                          const f16* __restrict__ Wc,
                                          f16* __restrict__ Cout, int M, int bid,
                                          f16* sA) {
    const int tid = threadIdx.x;
    const int row0 = bid * 64;

    if (A_F16) {
        const u32x4* src = (const u32x4*)Aptr;   // row-major [M][128] f16
        u32x4* dst = (u32x4*)sA;
        #pragma unroll
        for (int i = 0; i < 4; ++i) {
            int c = tid + i * 256;
            int r = c >> 4, ch = c & 15;
            int gr = row0 + r;
            u32x4 v = {};
            if (gr < M) v = src[gr * 16 + ch];
            dst[r * 16 + (ch ^ (r & 15))] = v;
        }
    } else {
        const float4* src = (const float4*)Aptr;   // fp32 x, row-major [M][128]
        u32x4* dst = (u32x4*)sA;
        #pragma unroll
        for (int i = 0; i < 4; ++i) {
            int c = tid + i * 256;
            int r = c >> 4, ch = c & 15;
            int gr = row0 + r;
            f16x8 h = {};
            if (gr < M) {
                float4 a = src[gr * 32 + ch * 2];
                float4 b = src[gr * 32 + ch * 2 + 1];
                h[0] = (f16)a.x; h[1] = (f16)a.y; h[2] = (f16)a.z; h[3] = (f16)a.w;
                h[4] = (f16)b.x; h[5] = (f16)b.y; h[6] = (f16)b.z; h[7] = (f16)b.w;
            }
            dst[r * 16 + (ch ^ (r & 15))] = *(const u32x4*)&h;
        }
    }
    __syncthreads();

    const int wave = tid >> 6, lane = tid & 63;
    const int m = lane & 15, kq = lane >> 4;
    const int wcol0 = wave * 32;

    f32x4 acc[4][2] = {};
    const f16x8* sa = (const f16x8*)sA;
    const f16x8* W8 = (const f16x8*)Wc;    // [128 rows][16 chunks]

    #pragma unroll
    for (int ks = 0; ks < 4; ++ks) {
        int cidx = ks * 4 + kq;
        f16x8 bfrag[2];
        #pragma unroll
        for (int cf = 0; cf < 2; ++cf)
            bfrag[cf] = W8[(wcol0 + cf * 16 + m) * 16 + cidx];   // direct from L2
        #pragma unroll
        for (int rf = 0; rf < 4; ++rf) {
            int ar = rf * 16 + m;
            f16x8 afrag = sa[ar * 16 + (cidx ^ m)];
            #pragma unroll
            for (int cf = 0; cf < 2; ++cf)
                acc[rf][cf] = __builtin_amdgcn_mfma_f32_16x16x32_f16(
                    afrag, bfrag[cf], acc[rf][cf], 0, 0, 0);
        }
    }

    __syncthreads();                 // done reading sA; reuse as output tile
    #pragma unroll
    for (int rf = 0; rf < 4; ++rf)
        #pragma unroll
        for (int cf = 0; cf < 2; ++cf)
            #pragma unroll
            for (int r = 0; r < 4; ++r)
                sA[(rf * 16 + kq * 4 + r) * 128 + wcol0 + cf * 16 + m] =
                    (f16)acc[rf][cf][r];
    __syncthreads();
    {
        const u32x4* src = (const u32x4*)sA;
        u32x4* dst = (u32x4*)Cout;
        #pragma unroll
        for (int i = 0; i < 4; ++i) {
            int c = tid + i * 256;
            int r = c >> 4, ch = c & 15;
            int gr = row0 + r;
            if (gr < M) dst[gr * 16 + ch] = src[c];
        }
    }
}

// ---------------- FUSED: GEMM1 blocks first + hist_fill4 blocks ----------------
// hist stores 8B {f32 w, u32 r} records (R15-measured-fastest form).

__global__ __launch_bounds__(256) void gemm1_hist(const float* __restrict__ x,
                                                  const f16* __restrict__ Wc1,
                                                  f16* __restrict__ Cout,
                                                  const int* __restrict__ ei,
                                                  const float* __restrict__ ew,
                                                  u64* __restrict__ dc,
                                                  u32x2* __restrict__ sed8,
                                                  int M, int E) {
    __shared__ f16 sA[64 * 128];
    if (blockIdx.x < GEMM1_BLOCKS) {
        gemm_body<false>(x, Wc1, Cout, M, blockIdx.x, sA);
        return;
    }
    // ---- hist_fill4 part: 4 consecutive edges per thread ----
    int t = (blockIdx.x - GEMM1_BLOCKS) * 256 + threadIdx.x;
    int e = 4 * t;
    if (e >= E) return;                       // E % 4 == 0 -> all 4 valid
    int4  r = *reinterpret_cast<const int4*>(ei + e);
    int4  c = *reinterpret_cast<const int4*>(ei + E + e);
    float4 w = *reinterpret_cast<const float4*>(ew + e);

    u64 old0 = 0, old1 = 0, old2 = 0, old3 = 0;
    bool k0 = r.x != c.x, k1 = r.y != c.y, k2 = r.z != c.z, k3 = r.w != c.w;
    if (k0) old0 = atomicAdd(&dc[c.x], (1ULL << 32) | (u64)(u32)__float2uint_rn(w.x * WSCALE));
    if (k1) old1 = atomicAdd(&dc[c.y], (1ULL << 32) | (u64)(u32)__float2uint_rn(w.y * WSCALE));
    if (k2) old2 = atomicAdd(&dc[c.z], (1ULL << 32) | (u64)(u32)__float2uint_rn(w.z * WSCALE));
    if (k3) old3 = atomicAdd(&dc[c.w], (1ULL << 32) | (u64)(u32)__float2uint_rn(w.w * WSCALE));

    u32x2 rec;
    if (k0) { rec.x = __float_as_uint(w.x); rec.y = (u32)r.x; sed8[(size_t)c.x * CAP + (u32)(old0 >> 32)] = rec; }
    if (k1) { rec.x = __float_as_uint(w.y); rec.y = (u32)r.y; sed8[(size_t)c.y * CAP + (u32)(old1 >> 32)] = rec; }
    if (k2) { rec.x = __float_as_uint(w.z); rec.y = (u32)r.z; sed8[(size_t)c.z * CAP + (u32)(old2 >> 32)] = rec; }
    if (k3) { rec.x = __float_as_uint(w.w); rec.y = (u32)r.w; sed8[(size_t)c.w * CAP + (u32)(old3 >> 32)] = rec; }
}

// plain GEMM wrapper for layer 2
__global__ __launch_bounds__(256) void gemm_l2(const f16* __restrict__ Aptr,
                                               const f16* __restrict__ Wc,
                                               f16* __restrict__ Cout, int M) {
    __shared__ f16 sA[64 * 128];
    gemm_body<true>(Aptr, Wc, Cout, M, blockIdx.x, sA);
}

// ---------------- bucket gather + fused epilogues (row-major [N][128] f16 src) ----

__device__ __forceinline__ void bucket_gather(const u32x2* __restrict__ eb,
                                              const u32* __restrict__ srcu,
                                              int pad, int lane,
                                              float& a0, float& a1) {
    for (int p = 0; p < pad; p += 16) {
        #pragma unroll
        for (int j = 0; j < 16; ++j) {
            u32x2 d = eb[p + j];
            float nm = __uint_as_float(d.x);
            __half2 hv = *reinterpret_cast<const __half2*>(&srcu[d.y + lane]);
            float2 v = __half22float2(hv);
            a0 += nm * v.x;
            a1 += nm * v.y;
        }
    }
}

// gather_relu WITH fused rewrite prologue: the wave converts its OWN bucket
// {f32 w, u32 r} -> {f32 norm, r*64} (lane-parallel, pad-zeroed) then gathers;
// re-reads are L1-hot. gather_out (later dispatch) sees rewritten buckets.
__global__ __launch_bounds__(256) void gather_relu(u32x2* __restrict__ sed8,
                                                   const u64* __restrict__ dc,
                                                   const f16* __restrict__ xw,  // [n][128]
                                                   const float* __restrict__ b,
                                                   f16* __restrict__ h, int n) { // [n][128]
    int wid = blockIdx.x * 4 + (threadIdx.x >> 6);
    int lane = threadIdx.x & 63;
    if (wid >= n) return;
    u32x2* eb = sed8 + (size_t)wid * CAP;
    u64 dcw = dc[wid];
    int cnt = (int)(dcw >> 32);
    int pad = (cnt + 15) & ~15;

    // ---- rewrite prologue (lane-parallel, wave-local) ----
    if (lane < pad) {
        u32x2 rec;
        if (lane < cnt) {
            u32x2 d = eb[lane];
            int r = (int)d.y;
            float w = __uint_as_float(d.x);
            float dis_own = rsqrtf(1.0f + wsum_of(dcw));
            float dis_r   = rsqrtf(1.0f + wsum_of(dc[r]));
            rec.x = __float_as_uint(dis_own * w * dis_r);
            rec.y = (u32)r * 64u;
        } else {
            rec.x = 0u; rec.y = (u32)(wid * 64);   // zero-weight pad
        }
        eb[lane] = rec;
    }

    const u32* srcu = (const u32*)xw;
    float a0 = 0.f, a1 = 0.f;
    bucket_gather(eb, srcu, pad, lane, a0, a1);
    float inv = 1.0f / (1.0f + wsum_of(dcw));   // 1/deg
    float2 xv = __half22float2(*reinterpret_cast<const __half2*>(&srcu[wid * 64 + lane]));
    float2 bb = reinterpret_cast<const float2*>(b)[lane];
    float o0 = fmaxf(a0 + xv.x * inv + bb.x, 0.f);
    float o1 = fmaxf(a1 + xv.y * inv + bb.y, 0.f);
    reinterpret_cast<__half2*>(h)[wid * 64 + lane] = __floats2half2_rn(o0, o1);
}

__global__ __launch_bounds__(256) void gather_out(const u32x2* __restrict__ sed8,
                                                  const u64* __restrict__ dc,
                                                  const f16* __restrict__ hw,  // [n][128]
                                                  const float* __restrict__ bmu,
                                                  const float* __restrict__ bls,
                                                  float* __restrict__ out, int n) {
    int wid = blockIdx.x * 4 + (threadIdx.x >> 6);
    int lane = threadIdx.x & 63;
    if (wid >= n) return;
    const u32* srcu = (const u32*)hw;
    u64 dcw = dc[wid];
    int cnt = (int)(dcw >> 32);
    int pad = (cnt + 15) & ~15;
    float a0 = 0.f, a1 = 0.f;
    bucket_gather(sed8 + (size_t)wid * CAP, srcu, pad, lane, a0, a1);
    float inv = 1.0f / (1.0f + wsum_of(dcw));
    float2 xv = __half22float2(*reinterpret_cast<const __half2*>(&srcu[wid * 64 + lane]));
    float2 bb = (lane < 32) ? reinterpret_cast<const float2*>(bmu)[lane]
                            : reinterpret_cast<const float2*>(bls)[lane - 32];
    float2 o = make_float2(a0 + xv.x * inv + bb.x, a1 + xv.y * inv + bb.y);
    // cols 0..63 (lanes 0..31) -> mu ; cols 64..127 (lanes 32..63) -> logstd
    if (lane < 32)
        reinterpret_cast<float2*>(out)[wid * 32 + lane] = o;
    else
        reinterpret_cast<float2*>(out + (size_t)n * 64)[wid * 32 + (lane - 32)] = o;
}

extern "C" void kernel_launch(void* const* d_in, const int* in_sizes, int n_in,
                              void* d_out, int out_size, void* d_ws, size_t ws_size,
                              hipStream_t stream) {
    const float* x   = (const float*)d_in[0];
    const int*   ei  = (const int*)d_in[1];
    const float* ew  = (const float*)d_in[2];
    const float* W1  = (const float*)d_in[3];
    const float* b1  = (const float*)d_in[4];
    const float* Wmu = (const float*)d_in[5];
    const float* bmu = (const float*)d_in[6];
    const float* Wls = (const float*)d_in[7];
    const float* bls = (const float*)d_in[8];
    float* out = (float*)d_out;

    // workspace layout (u32 units; all bases 16B-aligned)
    u64*   dc    = (u64*)d_ws;                       // 50000 u64 (100000 u32)
    u32x2* sed8  = (u32x2*)((u32*)d_ws + 100000);    // N*CAP u32x2 (25.6 MB)
    f16*   Wc1   = (f16*)((u32*)d_ws + 6500000);     // 16384 f16
    f16*   Wc2   = (f16*)((u32*)d_ws + 6508192);     // 16384 f16
    f16*   Abuf  = (f16*)((u32*)d_ws + 6516384);     // [N][128] f16 (xw -> hw)
    f16*   Hbuf  = (f16*)((u32*)d_ws + 9716384);     // [N][128] f16 (h)

    const int N = N_NODES, E = N_EDGES;
    const int NB = (N + 255) / 256;   // 196
    const int WB = (N + 3) / 4;       // wave-per-node kernels: 4 waves/block

    prep<<<NB, 256, 0, stream>>>(W1, Wmu, Wls, Wc1, Wc2, dc, N);

    // FUSED: layer-1 GEMM (first) + bucket-CSR histogram/fill
    gemm1_hist<<<GEMM1_BLOCKS + HIST_BLOCKS, 256, 0, stream>>>(
        x, Wc1, Abuf, ei, ew, dc, sed8, N, E);

    // gather_relu fuses the bucket rewrite as a wave-local prologue
    gather_relu<<<WB, 256, 0, stream>>>(sed8, dc, Abuf, b1, Hbuf, N);

    // layer 2 (mu‖logstd in one GEMM)
    gemm_l2<<<(N + 63) / 64, 256, 0, stream>>>(Hbuf, Wc2, Abuf, N);
    gather_out<<<WB, 256, 0, stream>>>(sed8, dc, Abuf, bmu, bls, out, N);
}